// Round 13
// baseline (131.926 us; speedup 1.0000x reference)
//
#include <hip/hip_runtime.h>
#include <cstdint>
#include <cstddef>

// mesh_features: [N_MESH=40962, 256] f32
// W1: [256,256], b1: [256], W2: [256,128], b2: [128]  (f32)
// edge_index: [2, E=400000] int32 (row0 = src mesh, row1 = dst grid)
// out: [N_GRID=100000, 128] f32
//
// Pipeline (uses silu(mean(msg)@W1+b1) == silu(mean(msg@W1)+b1)):
//   prep:   W1,W2 -> transposed fp16 + zero cnt (one kernel)
//   MERGED: gemm1 (meshW1 = mesh @ W1t) blocks + place (slot-CSR) blocks in one
//           heterogeneous grid (best-measured config, R10 vs R11 A/B).
//   FUSED:  agg_gemm2 — per 512-thr block: 16 nodes gathered by 8 waves
//           (2 nodes/wave, half-group, 8 rows in flight) into an 8.6 KB LDS
//           h-tile; barrier; each wave does one 16-col j-slice (8 MFMAs) of
//           out = h @ W2t + b2. h NEVER touches global memory.
//           (R8's failed fusion: 128 nodes/block, 16-deep serial gather,
//            67 KB LDS -> 2 blocks/CU. All three fixed here.)
//
// Determinism note: slot entries beyond a node's degree are STALE across graph
// replays (0xAA-poisoned on first call -> index 43690 > N_MESH). Indices for
// slot positions >= d MUST be clamped to a valid row (not just value-masked)
// because fmaf(NaN, 0, acc) == NaN.

typedef _Float16 half8 __attribute__((ext_vector_type(8)));
typedef float floatx4 __attribute__((ext_vector_type(4)));

// ---------- prep: transpose W1(256x256)+W2(256x128) -> fp16 [C][R]; zero cnt ----------
__global__ __launch_bounds__(256)
void prep_kernel(const float* __restrict__ W1, const float* __restrict__ W2,
                 _Float16* __restrict__ W1t, _Float16* __restrict__ W2t,
                 int* __restrict__ cnt, int NG) {
  int bid = (int)blockIdx.x;
  if (bid >= 96) {  // zero cnt: blocks 96.., 4KB each
    int idx = (bid - 96) * 1024 + (int)threadIdx.x * 4;
    if (idx + 3 < NG) *reinterpret_cast<int4*>(cnt + idx) = make_int4(0, 0, 0, 0);
    else { for (int k = 0; k < 4; ++k) if (idx + k < NG) cnt[idx + k] = 0; }
    return;
  }
  __shared__ float s[32][33];
  const float* src; _Float16* dst; int C, bx, by;
  if (bid < 64) { src = W1; dst = W1t; C = 256; bx = bid & 7; by = bid >> 3; }
  else { int id = bid - 64; src = W2; dst = W2t; C = 128; bx = id & 3; by = id >> 2; }
  const int R = 256;
  int tx = (int)(threadIdx.x & 31);
  int ty = (int)(threadIdx.x >> 5);
  int c0 = bx * 32, r0 = by * 32;
#pragma unroll
  for (int j = 0; j < 32; j += 8)
    s[ty + j][tx] = src[(size_t)(r0 + ty + j) * C + c0 + tx];
  __syncthreads();
#pragma unroll
  for (int j = 0; j < 32; j += 8)
    dst[(size_t)(c0 + ty + j) * R + r0 + tx] = (_Float16)s[tx][ty + j];
}

// ---------- MERGED: gemm1 blocks [0,nG1) + place blocks [nG1, nG1+nPl) ----------
__global__ __launch_bounds__(256)
void gemm1_place_kernel(const float* __restrict__ A, const _Float16* __restrict__ Bt,
                        _Float16* __restrict__ outh, int M, int nRowB, int nG1,
                        const int* __restrict__ ei, int* __restrict__ cnt,
                        unsigned short* __restrict__ slots, int E) {
  const int bid = (int)blockIdx.x;
  const int tid = (int)threadIdx.x;
  __shared__ _Float16 ldsB[64 * 264];

  if (bid >= nG1) {
    // ---- place branch ----
    int base = (bid - nG1) * 512;
    int e0 = base + tid;
    int e1 = base + 256 + tid;
    bool v0 = e0 < E, v1 = e1 < E;
    int s0 = 0, d0 = 0, s1 = 0, d1 = 0;
    if (v0) { s0 = ei[e0]; d0 = ei[E + e0]; }
    if (v1) { s1 = ei[e1]; d1 = ei[E + e1]; }
    if (v0) { int p = atomicAdd(&cnt[d0], 1);
              if (p < 32) slots[(size_t)d0 * 32 + p] = (unsigned short)s0; }
    if (v1) { int p = atomicAdd(&cnt[d1], 1);
              if (p < 32) slots[(size_t)d1 * 32 + p] = (unsigned short)s1; }
    return;
  }

  // ---- gemm1 branch ----
  const int cq = bid / nRowB;
  const int rb = bid % nRowB;
  const int c0 = cq * 64;

  for (int i = tid; i < 64 * 32; i += 256) {
    int col = i >> 5;
    int ch = i & 31;
    *reinterpret_cast<half8*>(&ldsB[col * 264 + ch * 8]) =
        *reinterpret_cast<const half8*>(&Bt[(size_t)(c0 + col) * 256 + ch * 8]);
  }
  __syncthreads();

  const int wid = tid >> 6;
  const int lane = tid & 63;
  const int r = lane & 15;
  const int kg = lane >> 4;
  const int mw = rb * 128 + wid * 32;

  int row0 = mw + r;       if (row0 > M - 1) row0 = M - 1;
  int row1 = mw + 16 + r;  if (row1 > M - 1) row1 = M - 1;
  const float* af0 = A + (size_t)row0 * 256 + kg * 8;
  const float* af1 = A + (size_t)row1 * 256 + kg * 8;

  floatx4 acc[2][4];
#pragma unroll
  for (int s = 0; s < 2; ++s)
#pragma unroll
    for (int j = 0; j < 4; ++j) acc[s][j] = (floatx4){0.f, 0.f, 0.f, 0.f};

#pragma unroll
  for (int k0 = 0; k0 < 256; k0 += 32) {
    float4 f0 = *reinterpret_cast<const float4*>(af0 + k0);
    float4 f1 = *reinterpret_cast<const float4*>(af0 + k0 + 4);
    float4 g0 = *reinterpret_cast<const float4*>(af1 + k0);
    float4 g1 = *reinterpret_cast<const float4*>(af1 + k0 + 4);
    half8 a0 = (half8){(_Float16)f0.x, (_Float16)f0.y, (_Float16)f0.z, (_Float16)f0.w,
                       (_Float16)f1.x, (_Float16)f1.y, (_Float16)f1.z, (_Float16)f1.w};
    half8 a1 = (half8){(_Float16)g0.x, (_Float16)g0.y, (_Float16)g0.z, (_Float16)g0.w,
                       (_Float16)g1.x, (_Float16)g1.y, (_Float16)g1.z, (_Float16)g1.w};
#pragma unroll
    for (int j = 0; j < 4; ++j) {
      half8 b = *reinterpret_cast<const half8*>(&ldsB[(j * 16 + r) * 264 + k0 + kg * 8]);
      acc[0][j] = __builtin_amdgcn_mfma_f32_16x16x32_f16(a0, b, acc[0][j], 0, 0, 0);
      acc[1][j] = __builtin_amdgcn_mfma_f32_16x16x32_f16(a1, b, acc[1][j], 0, 0, 0);
    }
  }

  const int crow = kg * 4;
#pragma unroll
  for (int s = 0; s < 2; ++s) {
#pragma unroll
    for (int j = 0; j < 4; ++j) {
      int n = c0 + j * 16 + r;
#pragma unroll
      for (int i = 0; i < 4; ++i) {
        int m = mw + s * 16 + crow + i;
        if (m < M) outh[(size_t)m * 256 + n] = (_Float16)acc[s][j][i];
      }
    }
  }
}

// ---------- FUSED agg+gemm2: 16 nodes/block, h-tile in LDS, out f32 ----------
__global__ __launch_bounds__(512)
void agg_gemm2_kernel(const _Float16* __restrict__ mW1, const int* __restrict__ cnt,
                      const unsigned short* __restrict__ slots,
                      const float* __restrict__ b1, const _Float16* __restrict__ W2t,
                      const float* __restrict__ b2, float* __restrict__ out, int NG) {
  __shared__ _Float16 hT[16 * 268];   // 268-pad: phase-A writes 4-way, B reads clean
  const int tid = (int)threadIdx.x;
  const int wid = tid >> 6;           // 0..7
  const int lane = tid & 63;
  const int half = lane >> 5;
  const int l32 = lane & 31;
  const int base = (int)blockIdx.x * 16;

  // ---- phase A: each half-group gathers+means+silus ONE node ----
  int gi = base + wid * 2 + half;
  bool valid = gi < NG;
  int g = valid ? gi : NG - 1;

  int d = cnt[g]; if (d > 32) d = 32;
  int sidx = (int)slots[(size_t)g * 32 + l32];
  const int sl0 = half * 32;

  float acc[8];
#pragma unroll
  for (int k = 0; k < 8; ++k) acc[k] = 0.f;

  for (int k = 0; k < d; k += 4) {
    int i0 = __shfl(sidx, sl0 + k + 0, 64);
    int i1 = __shfl(sidx, sl0 + k + 1, 64);
    int i2 = __shfl(sidx, sl0 + k + 2, 64);
    int i3 = __shfl(sidx, sl0 + k + 3, 64);
    if (k + 1 >= d) i1 = 0;   // clamp: stale slots may alias NaN-pattern memory
    if (k + 2 >= d) i2 = 0;
    if (k + 3 >= d) i3 = 0;
    half8 v0 = *reinterpret_cast<const half8*>(mW1 + (size_t)i0 * 256 + l32 * 8);
    half8 v1 = *reinterpret_cast<const half8*>(mW1 + (size_t)i1 * 256 + l32 * 8);
    half8 v2 = *reinterpret_cast<const half8*>(mW1 + (size_t)i2 * 256 + l32 * 8);
    half8 v3 = *reinterpret_cast<const half8*>(mW1 + (size_t)i3 * 256 + l32 * 8);
    float s1 = (k + 1 < d) ? 1.f : 0.f;
    float s2 = (k + 2 < d) ? 1.f : 0.f;
    float s3 = (k + 3 < d) ? 1.f : 0.f;
#pragma unroll
    for (int k8 = 0; k8 < 8; ++k8) {
      acc[k8] += (float)v0[k8];
      acc[k8] = fmaf((float)v1[k8], s1, acc[k8]);
      acc[k8] = fmaf((float)v2[k8], s2, acc[k8]);
      acc[k8] = fmaf((float)v3[k8], s3, acc[k8]);
    }
  }

  float rc = __builtin_amdgcn_rcpf(fmaxf((float)d, 1.0f));
  float4 blo = *reinterpret_cast<const float4*>(b1 + l32 * 8);
  float4 bhi = *reinterpret_cast<const float4*>(b1 + l32 * 8 + 4);
  float bb[8] = {blo.x, blo.y, blo.z, blo.w, bhi.x, bhi.y, bhi.z, bhi.w};
  half8 o;
#pragma unroll
  for (int k = 0; k < 8; ++k) {
    float x = fmaf(acc[k], rc, bb[k]);
    x = x * __builtin_amdgcn_rcpf(1.0f + __expf(-x));
    o[k] = (_Float16)x;
  }
  *reinterpret_cast<half8*>(&hT[(wid * 2 + half) * 268 + l32 * 8]) = o;

  __syncthreads();

  // ---- phase B: wave wid -> 16-col j-slice (cols wid*16..+15), 16 rows ----
  const int r = lane & 15;
  const int kg = lane >> 4;
  const _Float16* bp = W2t + (size_t)(wid * 16 + r) * 256 + kg * 8;

  floatx4 acc2 = (floatx4){0.f, 0.f, 0.f, 0.f};
#pragma unroll
  for (int k0 = 0; k0 < 256; k0 += 32) {
    half8 a = *reinterpret_cast<const half8*>(&hT[r * 268 + k0 + kg * 8]);
    half8 b = *reinterpret_cast<const half8*>(bp + k0);
    acc2 = __builtin_amdgcn_mfma_f32_16x16x32_f16(a, b, acc2, 0, 0, 0);
  }

  int n = wid * 16 + r;
  float bv = b2[n];
#pragma unroll
  for (int i = 0; i < 4; ++i) {
    int m = base + kg * 4 + i;
    if (m < NG) out[(size_t)m * 128 + n] = acc2[i] + bv;
  }
}

extern "C" void kernel_launch(void* const* d_in, const int* in_sizes, int n_in,
                              void* d_out, int out_size, void* d_ws, size_t ws_size,
                              hipStream_t stream) {
  const float* mesh = (const float*)d_in[0];
  const float* W1   = (const float*)d_in[1];
  const float* b1   = (const float*)d_in[2];
  const float* W2   = (const float*)d_in[3];
  const float* b2   = (const float*)d_in[4];
  const int*   ei   = (const int*)d_in[5];

  const int NM = in_sizes[0] / 256;   // 40962
  const int E  = in_sizes[5] / 2;     // 400000
  const int NG = out_size / 128;      // 100000

  // workspace layout (h eliminated)
  char* w = (char*)d_ws;
  _Float16* meshW1 = (_Float16*)w;                 w += (size_t)NM * 256 * 2;
  _Float16* W1t    = (_Float16*)w;                 w += 256 * 256 * 2;
  _Float16* W2t    = (_Float16*)w;                 w += 128 * 256 * 2;
  int* cnt = (int*)w;                              w += (size_t)NG * 4;
  unsigned short* slots = (unsigned short*)w;      w += (size_t)NG * 32 * 2;

  // prep: transposes (96 blocks) + cnt zero
  int zblk = (NG + 1023) / 1024;
  prep_kernel<<<96 + zblk, 256, 0, stream>>>(W1, W2, W1t, W2t, cnt, NG);

  // merged gemm1 + place
  int nRowB = (NM + 127) / 128;        // 321
  int nG1 = nRowB * 4;                 // 64-col quarters
  int nPl = (E + 511) / 512;           // 2 edges/thread
  gemm1_place_kernel<<<nG1 + nPl, 256, 0, stream>>>(
      mesh, W1t, meshW1, NM, nRowB, nG1, ei, cnt, slots, E);

  // fused aggregate + gemm2
  agg_gemm2_kernel<<<(NG + 15) / 16, 512, 0, stream>>>(
      meshW1, cnt, slots, b1, W2t, b2, (float*)d_out, NG);
}

// Round 14
// 104.792 us; speedup vs baseline: 1.2589x; 1.2589x over previous
//
#include <hip/hip_runtime.h>
#include <cstdint>
#include <cstddef>

// mesh_features: [N_MESH=40962, 256] f32
// W1: [256,256], b1: [256], W2: [256,128], b2: [128]  (f32)
// edge_index: [2, E=400000] int32 (row0 = src mesh, row1 = dst grid)
// out: [N_GRID=100000, 128] f32
//
// Pipeline (uses silu(mean(msg)@W1+b1) == silu(mean(msg@W1)+b1)):
//   prep:   W1,W2 -> transposed fp16 + zero cnt (one kernel)
//   MERGED: gemm1 + place in one heterogeneous grid. gemm1: per-wave A-frags
//           loaded ONCE to registers (A read 1x, was 4x in R10), then 4
//           sequential 64-col B-quarters staged in 33.8KB LDS.
//   aggregate: h = silu(segment_mean(meshW1)+b1)  (2 nodes/wave half-groups,
//              8 rows in flight; NO barrier coupling — R12 lesson: a barrier
//              after a Poisson-variable gather wastes ~half the issue slots)
//   gemm2:  out = h @ W2t + b2  (MFMA f16, LDS-staged B, f32 out)
//
// Determinism note: slot entries beyond a node's degree are STALE across graph
// replays (0xAA-poisoned on first call -> index 43690 > N_MESH). Indices for
// slot positions >= d MUST be clamped to a valid row (not just value-masked)
// because fmaf(NaN, 0, acc) == NaN.

typedef _Float16 half8 __attribute__((ext_vector_type(8)));
typedef float floatx4 __attribute__((ext_vector_type(4)));

// ---------- prep: transpose W1(256x256)+W2(256x128) -> fp16 [C][R]; zero cnt ----------
__global__ __launch_bounds__(256)
void prep_kernel(const float* __restrict__ W1, const float* __restrict__ W2,
                 _Float16* __restrict__ W1t, _Float16* __restrict__ W2t,
                 int* __restrict__ cnt, int NG) {
  int bid = (int)blockIdx.x;
  if (bid >= 96) {  // zero cnt
    int idx = (bid - 96) * 1024 + (int)threadIdx.x * 4;
    if (idx + 3 < NG) *reinterpret_cast<int4*>(cnt + idx) = make_int4(0, 0, 0, 0);
    else { for (int k = 0; k < 4; ++k) if (idx + k < NG) cnt[idx + k] = 0; }
    return;
  }
  __shared__ float s[32][33];
  const float* src; _Float16* dst; int C, bx, by;
  if (bid < 64) { src = W1; dst = W1t; C = 256; bx = bid & 7; by = bid >> 3; }
  else { int id = bid - 64; src = W2; dst = W2t; C = 128; bx = id & 3; by = id >> 2; }
  const int R = 256;
  int tx = (int)(threadIdx.x & 31);
  int ty = (int)(threadIdx.x >> 5);
  int c0 = bx * 32, r0 = by * 32;
#pragma unroll
  for (int j = 0; j < 32; j += 8)
    s[ty + j][tx] = src[(size_t)(r0 + ty + j) * C + c0 + tx];
  __syncthreads();
#pragma unroll
  for (int j = 0; j < 32; j += 8)
    dst[(size_t)(c0 + ty + j) * R + r0 + tx] = (_Float16)s[tx][ty + j];
}

// ---------- MERGED: gemm1 blocks [0,nG1) + place blocks [nG1, nG1+nPl) ----------
// gemm1: meshW1[M][256] = mesh_f32[M][256] @ W1t^T, fp16 out. 128 rows/block.
//   A-frags (16 half8/thread, 64 VGPRs) loaded once; 4 col-quarters staged
//   sequentially in 64x264 LDS (33.8KB -> 4 blocks/CU, place co-residency).
// place: 2 edges/thread, independent atomic chains.
__global__ __launch_bounds__(256)
void gemm1_place_kernel(const float* __restrict__ A, const _Float16* __restrict__ Bt,
                        _Float16* __restrict__ outh, int M, int nG1,
                        const int* __restrict__ ei, int* __restrict__ cnt,
                        unsigned short* __restrict__ slots, int E) {
  const int bid = (int)blockIdx.x;
  const int tid = (int)threadIdx.x;
  __shared__ _Float16 ldsB[64 * 264];

  if (bid >= nG1) {
    // ---- place branch ----
    int base = (bid - nG1) * 512;
    int e0 = base + tid;
    int e1 = base + 256 + tid;
    bool v0 = e0 < E, v1 = e1 < E;
    int s0 = 0, d0 = 0, s1 = 0, d1 = 0;
    if (v0) { s0 = ei[e0]; d0 = ei[E + e0]; }
    if (v1) { s1 = ei[e1]; d1 = ei[E + e1]; }
    if (v0) { int p = atomicAdd(&cnt[d0], 1);
              if (p < 32) slots[(size_t)d0 * 32 + p] = (unsigned short)s0; }
    if (v1) { int p = atomicAdd(&cnt[d1], 1);
              if (p < 32) slots[(size_t)d1 * 32 + p] = (unsigned short)s1; }
    return;
  }

  // ---- gemm1 branch ----
  const int wid = tid >> 6;
  const int lane = tid & 63;
  const int r = lane & 15;
  const int kg = lane >> 4;
  const int mw = bid * 128 + wid * 32;

  int row0 = mw + r;       if (row0 > M - 1) row0 = M - 1;
  int row1 = mw + 16 + r;  if (row1 > M - 1) row1 = M - 1;
  const float* af0 = A + (size_t)row0 * 256 + kg * 8;
  const float* af1 = A + (size_t)row1 * 256 + kg * 8;

  // load all A-fragments once (f32 -> f16 inline)
  half8 areg[2][8];
#pragma unroll
  for (int kk = 0; kk < 8; ++kk) {
    float4 f0 = *reinterpret_cast<const float4*>(af0 + kk * 32);
    float4 f1 = *reinterpret_cast<const float4*>(af0 + kk * 32 + 4);
    float4 g0 = *reinterpret_cast<const float4*>(af1 + kk * 32);
    float4 g1 = *reinterpret_cast<const float4*>(af1 + kk * 32 + 4);
    areg[0][kk] = (half8){(_Float16)f0.x, (_Float16)f0.y, (_Float16)f0.z, (_Float16)f0.w,
                          (_Float16)f1.x, (_Float16)f1.y, (_Float16)f1.z, (_Float16)f1.w};
    areg[1][kk] = (half8){(_Float16)g0.x, (_Float16)g0.y, (_Float16)g0.z, (_Float16)g0.w,
                          (_Float16)g1.x, (_Float16)g1.y, (_Float16)g1.z, (_Float16)g1.w};
  }

  for (int cq = 0; cq < 4; ++cq) {
    const int c0 = cq * 64;
    // stage B quarter (64 cols x 256 halves)
    for (int i = tid; i < 64 * 32; i += 256) {
      int col = i >> 5;
      int ch = i & 31;
      *reinterpret_cast<half8*>(&ldsB[col * 264 + ch * 8]) =
          *reinterpret_cast<const half8*>(&Bt[(size_t)(c0 + col) * 256 + ch * 8]);
    }
    __syncthreads();

    floatx4 acc[2][4];
#pragma unroll
    for (int s = 0; s < 2; ++s)
#pragma unroll
      for (int j = 0; j < 4; ++j) acc[s][j] = (floatx4){0.f, 0.f, 0.f, 0.f};

#pragma unroll
    for (int kk = 0; kk < 8; ++kk) {
#pragma unroll
      for (int j = 0; j < 4; ++j) {
        half8 b = *reinterpret_cast<const half8*>(&ldsB[(j * 16 + r) * 264 + kk * 32 + kg * 8]);
        acc[0][j] = __builtin_amdgcn_mfma_f32_16x16x32_f16(areg[0][kk], b, acc[0][j], 0, 0, 0);
        acc[1][j] = __builtin_amdgcn_mfma_f32_16x16x32_f16(areg[1][kk], b, acc[1][j], 0, 0, 0);
      }
    }

    const int crow = kg * 4;
#pragma unroll
    for (int s = 0; s < 2; ++s) {
#pragma unroll
      for (int j = 0; j < 4; ++j) {
        int n = c0 + j * 16 + r;
#pragma unroll
        for (int i = 0; i < 4; ++i) {
          int m = mw + s * 16 + crow + i;
          if (m < M) outh[(size_t)m * 256 + n] = (_Float16)acc[s][j][i];
        }
      }
    }
    __syncthreads();   // before next quarter overwrites ldsB
  }
}

// ---------- aggregate: h = silu(mean(meshW1 rows) + b1), fp16 out ----------
// One node per 32-lane HALF-group (2 nodes/wave). 4 slot-rows in flight per
// half (8 per wave); indices shfl-fed from one lane-parallel slot load.
__global__ __launch_bounds__(256)
void aggregate_kernel(const _Float16* __restrict__ mW1, const int* __restrict__ cnt,
                      const unsigned short* __restrict__ slots,
                      const float* __restrict__ b1, _Float16* __restrict__ h, int NG) {
  int wave = (int)((blockIdx.x * 256u + threadIdx.x) >> 6);
  int lane = (int)(threadIdx.x & 63);
  int half = lane >> 5;
  int l32 = lane & 31;
  int gi = wave * 2 + half;
  bool valid = gi < NG;
  int g = valid ? gi : NG - 1;

  int d = cnt[g]; if (d > 32) d = 32;
  int sidx = (int)slots[(size_t)g * 32 + l32];
  const int sl0 = half * 32;

  float acc[8];
#pragma unroll
  for (int k = 0; k < 8; ++k) acc[k] = 0.f;

  for (int k = 0; k < d; k += 4) {
    int i0 = __shfl(sidx, sl0 + k + 0, 64);
    int i1 = __shfl(sidx, sl0 + k + 1, 64);
    int i2 = __shfl(sidx, sl0 + k + 2, 64);
    int i3 = __shfl(sidx, sl0 + k + 3, 64);
    if (k + 1 >= d) i1 = 0;   // clamp: stale slots may alias NaN-pattern memory
    if (k + 2 >= d) i2 = 0;
    if (k + 3 >= d) i3 = 0;
    half8 v0 = *reinterpret_cast<const half8*>(mW1 + (size_t)i0 * 256 + l32 * 8);
    half8 v1 = *reinterpret_cast<const half8*>(mW1 + (size_t)i1 * 256 + l32 * 8);
    half8 v2 = *reinterpret_cast<const half8*>(mW1 + (size_t)i2 * 256 + l32 * 8);
    half8 v3 = *reinterpret_cast<const half8*>(mW1 + (size_t)i3 * 256 + l32 * 8);
    float s1 = (k + 1 < d) ? 1.f : 0.f;
    float s2 = (k + 2 < d) ? 1.f : 0.f;
    float s3 = (k + 3 < d) ? 1.f : 0.f;
#pragma unroll
    for (int k8 = 0; k8 < 8; ++k8) {
      acc[k8] += (float)v0[k8];
      acc[k8] = fmaf((float)v1[k8], s1, acc[k8]);
      acc[k8] = fmaf((float)v2[k8], s2, acc[k8]);
      acc[k8] = fmaf((float)v3[k8], s3, acc[k8]);
    }
  }

  float rc = __builtin_amdgcn_rcpf(fmaxf((float)d, 1.0f));
  float4 blo = *reinterpret_cast<const float4*>(b1 + l32 * 8);
  float4 bhi = *reinterpret_cast<const float4*>(b1 + l32 * 8 + 4);
  float bb[8] = {blo.x, blo.y, blo.z, blo.w, bhi.x, bhi.y, bhi.z, bhi.w};
  half8 o;
#pragma unroll
  for (int k = 0; k < 8; ++k) {
    float x = fmaf(acc[k], rc, bb[k]);
    x = x * __builtin_amdgcn_rcpf(1.0f + __expf(-x));
    o[k] = (_Float16)x;
  }
  if (valid)
    *reinterpret_cast<half8*>(h + (size_t)g * 256 + l32 * 8) = o;
}

// ---------- gemm2: out[M][128] = h[M][256] @ W2t^T + b2, f32 out ----------
__global__ __launch_bounds__(256)
void mfma_gemm2(const _Float16* __restrict__ A, const _Float16* __restrict__ Bt,
                const float* __restrict__ bias, float* __restrict__ outf, int M) {
  __shared__ _Float16 ldsB[128 * 264];
  const int tid = (int)threadIdx.x;

  for (int i = tid; i < 128 * 32; i += 256) {
    int col = i >> 5;
    int ch = i & 31;
    *reinterpret_cast<half8*>(&ldsB[col * 264 + ch * 8]) =
        *reinterpret_cast<const half8*>(&Bt[(size_t)col * 256 + ch * 8]);
  }
  __syncthreads();

  const int wid = tid >> 6;
  const int lane = tid & 63;
  const int r = lane & 15;
  const int kg = lane >> 4;
  const int mw = (int)blockIdx.x * 128 + wid * 32;

  int row0 = mw + r;       if (row0 > M - 1) row0 = M - 1;
  int row1 = mw + 16 + r;  if (row1 > M - 1) row1 = M - 1;
  const _Float16* ah0 = A + (size_t)row0 * 256 + kg * 8;
  const _Float16* ah1 = A + (size_t)row1 * 256 + kg * 8;

  floatx4 acc[2][8];
#pragma unroll
  for (int s = 0; s < 2; ++s)
#pragma unroll
    for (int j = 0; j < 8; ++j) acc[s][j] = (floatx4){0.f, 0.f, 0.f, 0.f};

#pragma unroll
  for (int k0 = 0; k0 < 256; k0 += 32) {
    half8 a0 = *reinterpret_cast<const half8*>(ah0 + k0);
    half8 a1 = *reinterpret_cast<const half8*>(ah1 + k0);
#pragma unroll
    for (int j = 0; j < 8; ++j) {
      half8 b = *reinterpret_cast<const half8*>(&ldsB[(j * 16 + r) * 264 + k0 + kg * 8]);
      acc[0][j] = __builtin_amdgcn_mfma_f32_16x16x32_f16(a0, b, acc[0][j], 0, 0, 0);
      acc[1][j] = __builtin_amdgcn_mfma_f32_16x16x32_f16(a1, b, acc[1][j], 0, 0, 0);
    }
  }

  const int crow = kg * 4;
#pragma unroll
  for (int s = 0; s < 2; ++s) {
#pragma unroll
    for (int j = 0; j < 8; ++j) {
      int n = j * 16 + r;
      float bv = bias[n];
#pragma unroll
      for (int i = 0; i < 4; ++i) {
        int m = mw + s * 16 + crow + i;
        if (m < M) outf[(size_t)m * 128 + n] = acc[s][j][i] + bv;
      }
    }
  }
}

extern "C" void kernel_launch(void* const* d_in, const int* in_sizes, int n_in,
                              void* d_out, int out_size, void* d_ws, size_t ws_size,
                              hipStream_t stream) {
  const float* mesh = (const float*)d_in[0];
  const float* W1   = (const float*)d_in[1];
  const float* b1   = (const float*)d_in[2];
  const float* W2   = (const float*)d_in[3];
  const float* b2   = (const float*)d_in[4];
  const int*   ei   = (const int*)d_in[5];

  const int NM = in_sizes[0] / 256;   // 40962
  const int E  = in_sizes[5] / 2;     // 400000
  const int NG = out_size / 128;      // 100000

  // workspace layout
  char* w = (char*)d_ws;
  _Float16* meshW1 = (_Float16*)w;                 w += (size_t)NM * 256 * 2;
  _Float16* h      = (_Float16*)w;                 w += (size_t)NG * 256 * 2;
  _Float16* W1t    = (_Float16*)w;                 w += 256 * 256 * 2;
  _Float16* W2t    = (_Float16*)w;                 w += 128 * 256 * 2;
  int* cnt = (int*)w;                              w += (size_t)NG * 4;
  unsigned short* slots = (unsigned short*)w;      w += (size_t)NG * 32 * 2;

  // prep: transposes (96 blocks) + cnt zero
  int zblk = (NG + 1023) / 1024;
  prep_kernel<<<96 + zblk, 256, 0, stream>>>(W1, W2, W1t, W2t, cnt, NG);

  // merged gemm1 (A read once, 4 col-quarters) + place
  int nG1 = (NM + 127) / 128;          // 321
  int nPl = (E + 511) / 512;           // 782
  gemm1_place_kernel<<<nG1 + nPl, 256, 0, stream>>>(
      mesh, W1t, meshW1, NM, nG1, ei, cnt, slots, E);

  // h = silu(mean + b1)
  aggregate_kernel<<<(NG + 7) / 8, 256, 0, stream>>>(meshW1, cnt, slots, b1, h, NG);

  // out = h @ W2t^T + b2
  mfma_gemm2<<<(NG + 127) / 128, 256, 0, stream>>>(h, W2t, b2, (float*)d_out, NG);
}

// Round 15
// 94.007 us; speedup vs baseline: 1.4034x; 1.1147x over previous
//
#include <hip/hip_runtime.h>
#include <cstdint>
#include <cstddef>

// mesh_features: [N_MESH=40962, 256] f32
// W1: [256,256], b1: [256], W2: [256,128], b2: [128]  (f32)
// edge_index: [2, E=400000] int32 (row0 = src mesh, row1 = dst grid)
// out: [N_GRID=100000, 128] f32
//
// Pipeline (uses silu(mean(msg)@W1+b1) == silu(mean(msg@W1)+b1)):
//   prep:   W1,W2 -> transposed fp16 + zero cnt (one kernel)
//   MERGED: gemm1 + place heterogeneous grid; gemm1 loads A-frags ONCE to
//           registers then loops 4 B-quarters in 33.8KB LDS (R13: 124.9->104.8)
//   aggregate: h = silu(segment_mean(meshW1)+b1). TWO nodes per 32-lane half
//              (4/wave) -> 8 row-loads in flight per half, 16 per wave.
//   gemm2:  out = h @ W2t + b2. 512 thr / 256 rows per block (B-staging halved,
//           16 waves/CU under 67.6KB LDS).
//
// Determinism note: slot entries beyond a node's degree are STALE across graph
// replays (0xAA-poisoned on first call -> index 43690 > N_MESH). Indices for
// slot positions >= d MUST be clamped to a valid row (not just value-masked)
// because fmaf(NaN, 0, acc) == NaN.
// R12 lesson: never barrier-couple the Poisson-variable gather to uniform
// MFMA work — slowest-of-block gather stalls all issue slots.

typedef _Float16 half8 __attribute__((ext_vector_type(8)));
typedef float floatx4 __attribute__((ext_vector_type(4)));

// ---------- prep: transpose W1(256x256)+W2(256x128) -> fp16 [C][R]; zero cnt ----------
__global__ __launch_bounds__(256)
void prep_kernel(const float* __restrict__ W1, const float* __restrict__ W2,
                 _Float16* __restrict__ W1t, _Float16* __restrict__ W2t,
                 int* __restrict__ cnt, int NG) {
  int bid = (int)blockIdx.x;
  if (bid >= 96) {  // zero cnt
    int idx = (bid - 96) * 1024 + (int)threadIdx.x * 4;
    if (idx + 3 < NG) *reinterpret_cast<int4*>(cnt + idx) = make_int4(0, 0, 0, 0);
    else { for (int k = 0; k < 4; ++k) if (idx + k < NG) cnt[idx + k] = 0; }
    return;
  }
  __shared__ float s[32][33];
  const float* src; _Float16* dst; int C, bx, by;
  if (bid < 64) { src = W1; dst = W1t; C = 256; bx = bid & 7; by = bid >> 3; }
  else { int id = bid - 64; src = W2; dst = W2t; C = 128; bx = id & 3; by = id >> 2; }
  const int R = 256;
  int tx = (int)(threadIdx.x & 31);
  int ty = (int)(threadIdx.x >> 5);
  int c0 = bx * 32, r0 = by * 32;
#pragma unroll
  for (int j = 0; j < 32; j += 8)
    s[ty + j][tx] = src[(size_t)(r0 + ty + j) * C + c0 + tx];
  __syncthreads();
#pragma unroll
  for (int j = 0; j < 32; j += 8)
    dst[(size_t)(c0 + ty + j) * R + r0 + tx] = (_Float16)s[tx][ty + j];
}

// ---------- MERGED: gemm1 blocks [0,nG1) + place blocks [nG1, nG1+nPl) ----------
__global__ __launch_bounds__(256)
void gemm1_place_kernel(const float* __restrict__ A, const _Float16* __restrict__ Bt,
                        _Float16* __restrict__ outh, int M, int nG1,
                        const int* __restrict__ ei, int* __restrict__ cnt,
                        unsigned short* __restrict__ slots, int E) {
  const int bid = (int)blockIdx.x;
  const int tid = (int)threadIdx.x;
  __shared__ _Float16 ldsB[64 * 264];

  if (bid >= nG1) {
    // ---- place branch ----
    int base = (bid - nG1) * 512;
    int e0 = base + tid;
    int e1 = base + 256 + tid;
    bool v0 = e0 < E, v1 = e1 < E;
    int s0 = 0, d0 = 0, s1 = 0, d1 = 0;
    if (v0) { s0 = ei[e0]; d0 = ei[E + e0]; }
    if (v1) { s1 = ei[e1]; d1 = ei[E + e1]; }
    if (v0) { int p = atomicAdd(&cnt[d0], 1);
              if (p < 32) slots[(size_t)d0 * 32 + p] = (unsigned short)s0; }
    if (v1) { int p = atomicAdd(&cnt[d1], 1);
              if (p < 32) slots[(size_t)d1 * 32 + p] = (unsigned short)s1; }
    return;
  }

  // ---- gemm1 branch ----
  const int wid = tid >> 6;
  const int lane = tid & 63;
  const int r = lane & 15;
  const int kg = lane >> 4;
  const int mw = bid * 128 + wid * 32;

  int row0 = mw + r;       if (row0 > M - 1) row0 = M - 1;
  int row1 = mw + 16 + r;  if (row1 > M - 1) row1 = M - 1;
  const float* af0 = A + (size_t)row0 * 256 + kg * 8;
  const float* af1 = A + (size_t)row1 * 256 + kg * 8;

  half8 areg[2][8];
#pragma unroll
  for (int kk = 0; kk < 8; ++kk) {
    float4 f0 = *reinterpret_cast<const float4*>(af0 + kk * 32);
    float4 f1 = *reinterpret_cast<const float4*>(af0 + kk * 32 + 4);
    float4 g0 = *reinterpret_cast<const float4*>(af1 + kk * 32);
    float4 g1 = *reinterpret_cast<const float4*>(af1 + kk * 32 + 4);
    areg[0][kk] = (half8){(_Float16)f0.x, (_Float16)f0.y, (_Float16)f0.z, (_Float16)f0.w,
                          (_Float16)f1.x, (_Float16)f1.y, (_Float16)f1.z, (_Float16)f1.w};
    areg[1][kk] = (half8){(_Float16)g0.x, (_Float16)g0.y, (_Float16)g0.z, (_Float16)g0.w,
                          (_Float16)g1.x, (_Float16)g1.y, (_Float16)g1.z, (_Float16)g1.w};
  }

  for (int cq = 0; cq < 4; ++cq) {
    const int c0 = cq * 64;
    for (int i = tid; i < 64 * 32; i += 256) {
      int col = i >> 5;
      int ch = i & 31;
      *reinterpret_cast<half8*>(&ldsB[col * 264 + ch * 8]) =
          *reinterpret_cast<const half8*>(&Bt[(size_t)(c0 + col) * 256 + ch * 8]);
    }
    __syncthreads();

    floatx4 acc[2][4];
#pragma unroll
    for (int s = 0; s < 2; ++s)
#pragma unroll
      for (int j = 0; j < 4; ++j) acc[s][j] = (floatx4){0.f, 0.f, 0.f, 0.f};

#pragma unroll
    for (int kk = 0; kk < 8; ++kk) {
#pragma unroll
      for (int j = 0; j < 4; ++j) {
        half8 b = *reinterpret_cast<const half8*>(&ldsB[(j * 16 + r) * 264 + kk * 32 + kg * 8]);
        acc[0][j] = __builtin_amdgcn_mfma_f32_16x16x32_f16(areg[0][kk], b, acc[0][j], 0, 0, 0);
        acc[1][j] = __builtin_amdgcn_mfma_f32_16x16x32_f16(areg[1][kk], b, acc[1][j], 0, 0, 0);
      }
    }

    const int crow = kg * 4;
#pragma unroll
    for (int s = 0; s < 2; ++s) {
#pragma unroll
      for (int j = 0; j < 4; ++j) {
        int n = c0 + j * 16 + r;
#pragma unroll
        for (int i = 0; i < 4; ++i) {
          int m = mw + s * 16 + crow + i;
          if (m < M) outh[(size_t)m * 256 + n] = (_Float16)acc[s][j][i];
        }
      }
    }
    __syncthreads();
  }
}

// ---------- aggregate: h = silu(mean(meshW1 rows) + b1), fp16 out ----------
// TWO nodes per 32-lane half (4 nodes/wave, 16 per 256-thr block). Unified
// kmax loop issues up to 8 independent half8 row-loads per half per iter.
__global__ __launch_bounds__(256)
void aggregate_kernel(const _Float16* __restrict__ mW1, const int* __restrict__ cnt,
                      const unsigned short* __restrict__ slots,
                      const float* __restrict__ b1, _Float16* __restrict__ h, int NG) {
  int wave = (int)((blockIdx.x * 256u + threadIdx.x) >> 6);
  int lane = (int)(threadIdx.x & 63);
  int half = lane >> 5;
  int l32 = lane & 31;
  int gA = wave * 4 + half * 2;
  int gB = gA + 1;
  bool vA = gA < NG, vB = gB < NG;
  int ga = vA ? gA : NG - 1;
  int gb = vB ? gB : NG - 1;

  int dA = cnt[ga]; if (dA > 32) dA = 32;
  int dB = cnt[gb]; if (dB > 32) dB = 32;
  int sA = (int)slots[(size_t)ga * 32 + l32];
  int sB = (int)slots[(size_t)gb * 32 + l32];
  const int sl0 = half * 32;

  float accA[8], accB[8];
#pragma unroll
  for (int k = 0; k < 8; ++k) { accA[k] = 0.f; accB[k] = 0.f; }

  int kmax = dA > dB ? dA : dB;
  for (int k = 0; k < kmax; k += 4) {
    int ia0 = __shfl(sA, sl0 + k + 0, 64);
    int ia1 = __shfl(sA, sl0 + k + 1, 64);
    int ia2 = __shfl(sA, sl0 + k + 2, 64);
    int ia3 = __shfl(sA, sl0 + k + 3, 64);
    int ib0 = __shfl(sB, sl0 + k + 0, 64);
    int ib1 = __shfl(sB, sl0 + k + 1, 64);
    int ib2 = __shfl(sB, sl0 + k + 2, 64);
    int ib3 = __shfl(sB, sl0 + k + 3, 64);
    // clamp: stale slots may alias NaN-pattern memory (see determinism note)
    if (k + 0 >= dA) ia0 = 0;  if (k + 1 >= dA) ia1 = 0;
    if (k + 2 >= dA) ia2 = 0;  if (k + 3 >= dA) ia3 = 0;
    if (k + 0 >= dB) ib0 = 0;  if (k + 1 >= dB) ib1 = 0;
    if (k + 2 >= dB) ib2 = 0;  if (k + 3 >= dB) ib3 = 0;
    half8 va0 = *reinterpret_cast<const half8*>(mW1 + (size_t)ia0 * 256 + l32 * 8);
    half8 va1 = *reinterpret_cast<const half8*>(mW1 + (size_t)ia1 * 256 + l32 * 8);
    half8 va2 = *reinterpret_cast<const half8*>(mW1 + (size_t)ia2 * 256 + l32 * 8);
    half8 va3 = *reinterpret_cast<const half8*>(mW1 + (size_t)ia3 * 256 + l32 * 8);
    half8 vb0 = *reinterpret_cast<const half8*>(mW1 + (size_t)ib0 * 256 + l32 * 8);
    half8 vb1 = *reinterpret_cast<const half8*>(mW1 + (size_t)ib1 * 256 + l32 * 8);
    half8 vb2 = *reinterpret_cast<const half8*>(mW1 + (size_t)ib2 * 256 + l32 * 8);
    half8 vb3 = *reinterpret_cast<const half8*>(mW1 + (size_t)ib3 * 256 + l32 * 8);
    float a0 = (k + 0 < dA) ? 1.f : 0.f;
    float a1 = (k + 1 < dA) ? 1.f : 0.f;
    float a2 = (k + 2 < dA) ? 1.f : 0.f;
    float a3 = (k + 3 < dA) ? 1.f : 0.f;
    float b0 = (k + 0 < dB) ? 1.f : 0.f;
    float b1s = (k + 1 < dB) ? 1.f : 0.f;
    float b2s = (k + 2 < dB) ? 1.f : 0.f;
    float b3 = (k + 3 < dB) ? 1.f : 0.f;
#pragma unroll
    for (int k8 = 0; k8 < 8; ++k8) {
      accA[k8] = fmaf((float)va0[k8], a0, accA[k8]);
      accA[k8] = fmaf((float)va1[k8], a1, accA[k8]);
      accA[k8] = fmaf((float)va2[k8], a2, accA[k8]);
      accA[k8] = fmaf((float)va3[k8], a3, accA[k8]);
      accB[k8] = fmaf((float)vb0[k8], b0, accB[k8]);
      accB[k8] = fmaf((float)vb1[k8], b1s, accB[k8]);
      accB[k8] = fmaf((float)vb2[k8], b2s, accB[k8]);
      accB[k8] = fmaf((float)vb3[k8], b3, accB[k8]);
    }
  }

  float rcA = __builtin_amdgcn_rcpf(fmaxf((float)dA, 1.0f));
  float rcB = __builtin_amdgcn_rcpf(fmaxf((float)dB, 1.0f));
  float4 blo = *reinterpret_cast<const float4*>(b1 + l32 * 8);
  float4 bhi = *reinterpret_cast<const float4*>(b1 + l32 * 8 + 4);
  float bb[8] = {blo.x, blo.y, blo.z, blo.w, bhi.x, bhi.y, bhi.z, bhi.w};
  half8 oA, oB;
#pragma unroll
  for (int k = 0; k < 8; ++k) {
    float xA = fmaf(accA[k], rcA, bb[k]);
    xA = xA * __builtin_amdgcn_rcpf(1.0f + __expf(-xA));
    oA[k] = (_Float16)xA;
    float xB = fmaf(accB[k], rcB, bb[k]);
    xB = xB * __builtin_amdgcn_rcpf(1.0f + __expf(-xB));
    oB[k] = (_Float16)xB;
  }
  if (vA) *reinterpret_cast<half8*>(h + (size_t)ga * 256 + l32 * 8) = oA;
  if (vB) *reinterpret_cast<half8*>(h + (size_t)gb * 256 + l32 * 8) = oB;
}

// ---------- gemm2: out[M][128] = h[M][256] @ W2t^T + b2, f32 out ----------
// 512 thr = 8 waves, 256 rows/block (32/wave) — B staged once per 256 rows.
__global__ __launch_bounds__(512)
void mfma_gemm2(const _Float16* __restrict__ A, const _Float16* __restrict__ Bt,
                const float* __restrict__ bias, float* __restrict__ outf, int M) {
  __shared__ _Float16 ldsB[128 * 264];
  const int tid = (int)threadIdx.x;

  for (int i = tid; i < 128 * 32; i += 512) {
    int col = i >> 5;
    int ch = i & 31;
    *reinterpret_cast<half8*>(&ldsB[col * 264 + ch * 8]) =
        *reinterpret_cast<const half8*>(&Bt[(size_t)col * 256 + ch * 8]);
  }
  __syncthreads();

  const int wid = tid >> 6;
  const int lane = tid & 63;
  const int r = lane & 15;
  const int kg = lane >> 4;
  const int mw = (int)blockIdx.x * 256 + wid * 32;

  int row0 = mw + r;       if (row0 > M - 1) row0 = M - 1;
  int row1 = mw + 16 + r;  if (row1 > M - 1) row1 = M - 1;
  const _Float16* ah0 = A + (size_t)row0 * 256 + kg * 8;
  const _Float16* ah1 = A + (size_t)row1 * 256 + kg * 8;

  floatx4 acc[2][8];
#pragma unroll
  for (int s = 0; s < 2; ++s)
#pragma unroll
    for (int j = 0; j < 8; ++j) acc[s][j] = (floatx4){0.f, 0.f, 0.f, 0.f};

#pragma unroll
  for (int k0 = 0; k0 < 256; k0 += 32) {
    half8 a0 = *reinterpret_cast<const half8*>(ah0 + k0);
    half8 a1 = *reinterpret_cast<const half8*>(ah1 + k0);
#pragma unroll
    for (int j = 0; j < 8; ++j) {
      half8 b = *reinterpret_cast<const half8*>(&ldsB[(j * 16 + r) * 264 + k0 + kg * 8]);
      acc[0][j] = __builtin_amdgcn_mfma_f32_16x16x32_f16(a0, b, acc[0][j], 0, 0, 0);
      acc[1][j] = __builtin_amdgcn_mfma_f32_16x16x32_f16(a1, b, acc[1][j], 0, 0, 0);
    }
  }

  const int crow = kg * 4;
#pragma unroll
  for (int s = 0; s < 2; ++s) {
#pragma unroll
    for (int j = 0; j < 8; ++j) {
      int n = j * 16 + r;
      float bv = bias[n];
#pragma unroll
      for (int i = 0; i < 4; ++i) {
        int m = mw + s * 16 + crow + i;
        if (m < M) outf[(size_t)m * 128 + n] = acc[s][j][i] + bv;
      }
    }
  }
}

extern "C" void kernel_launch(void* const* d_in, const int* in_sizes, int n_in,
                              void* d_out, int out_size, void* d_ws, size_t ws_size,
                              hipStream_t stream) {
  const float* mesh = (const float*)d_in[0];
  const float* W1   = (const float*)d_in[1];
  const float* b1   = (const float*)d_in[2];
  const float* W2   = (const float*)d_in[3];
  const float* b2   = (const float*)d_in[4];
  const int*   ei   = (const int*)d_in[5];

  const int NM = in_sizes[0] / 256;   // 40962
  const int E  = in_sizes[5] / 2;     // 400000
  const int NG = out_size / 128;      // 100000

  // workspace layout
  char* w = (char*)d_ws;
  _Float16* meshW1 = (_Float16*)w;                 w += (size_t)NM * 256 * 2;
  _Float16* h      = (_Float16*)w;                 w += (size_t)NG * 256 * 2;
  _Float16* W1t    = (_Float16*)w;                 w += 256 * 256 * 2;
  _Float16* W2t    = (_Float16*)w;                 w += 128 * 256 * 2;
  int* cnt = (int*)w;                              w += (size_t)NG * 4;
  unsigned short* slots = (unsigned short*)w;      w += (size_t)NG * 32 * 2;

  // prep: transposes (96 blocks) + cnt zero
  int zblk = (NG + 1023) / 1024;
  prep_kernel<<<96 + zblk, 256, 0, stream>>>(W1, W2, W1t, W2t, cnt, NG);

  // merged gemm1 (A read once, 4 col-quarters) + place
  int nG1 = (NM + 127) / 128;          // 321
  int nPl = (E + 511) / 512;           // 782
  gemm1_place_kernel<<<nG1 + nPl, 256, 0, stream>>>(
      mesh, W1t, meshW1, NM, nG1, ei, cnt, slots, E);

  // h = silu(mean + b1)  (4 nodes/wave, 16 rows in flight)
  aggregate_kernel<<<(NG + 15) / 16, 256, 0, stream>>>(meshW1, cnt, slots, b1, h, NG);

  // out = h @ W2t^T + b2  (256 rows/block)
  mfma_gemm2<<<(NG + 255) / 256, 512, 0, stream>>>(h, W2t, b2, (float*)d_out, NG);
}